// Round 14
// baseline (265.683 us; speedup 1.0000x reference)
//
#include <hip/hip_runtime.h>
#include <hip/hip_fp16.h>
#include <math.h>

#define HW 512
#define MASK 511
#define IMG (512*512)
#define NSTEP 16
#define NSLICE 17

#define TR 84             // tile rows: [Y0-10, Y0+74)
#define TSTR 96           // halfs per row (192B = 12 granules; DMA-linear, banks uniform)
#define WSB_OFF 32        // ushort offset of B-frag table in ws
#define HBUF_OFF_BYTES (4u << 20)   // fp16 state ping-pong buffer at ws+4MB

typedef _Float16 half_t;
typedef __attribute__((ext_vector_type(8))) _Float16 f16x8;
typedef __attribute__((ext_vector_type(4))) _Float16 f16x4;
typedef __attribute__((ext_vector_type(4))) float f32x4;

#define SBAR() __builtin_amdgcn_sched_barrier(0)

// B-frags (Toeplitz): frag f2 = dy*4 + v*2 + s  (v: dx-window, s: hi/lo split).
// lane l, elem j -> k = 8*(l>>4)+j, n = l&15, d = k-n.
// v=0: B[k][n] = W[dy][d-6]  for d in [6,15]  (dx 0..9,  A-window 16j)
// v=1: B[k][n] = W[dy][d+10] for d in [0,10]  (dx 10..20, A-window 16j+16)
// W = W_h + W_l (fp16 split) => W effectively exact; x is single fp16 (2-pass).
__global__ void prep_kernel(const float* __restrict__ w1,
                            const float* __restrict__ w2,
                            const float* __restrict__ w3,
                            float* __restrict__ ws) {
    int tid = threadIdx.x;
    if (tid == 0) {
        // 1->10->1 MLP on nonneg scalar collapses: C = sum_o w3[o]*max(w2[o],0)
        float c = 0.f;
        for (int o = 0; o < 10; ++o) c += w3[o] * fmaxf(w2[o], 0.f);
        ws[0] = c;
    }
    half_t* wsb = (half_t*)((unsigned short*)ws + WSB_OFF);
    for (int u = tid; u < 84 * 512; u += blockDim.x) {
        int f2 = u >> 9, rem = u & 511, l = rem >> 3, j = rem & 7;
        int dy = f2 >> 2, v = (f2 >> 1) & 1, s = f2 & 1;
        int k = ((l >> 4) << 3) + j, n = l & 15, d = k - n;
        float wf = 0.f;
        if (v == 0) { if (d >= 6 && d <= 15) wf = w1[dy * 21 + d - 6]; }
        else        { if (d >= 0 && d <= 10) wf = w1[dy * 21 + d + 10]; }
        half_t h = (half_t)wf;
        wsb[u] = (s == 0) ? h : (half_t)(wf - (float)h);   // W = W_h + W_l
    }
}

// copy slice 0 (fp32) + seed fp16 state buffer parity 0
__global__ void copy_kernel(const float* __restrict__ x, float* __restrict__ out,
                            half_t* __restrict__ hbuf) {
    int i = blockIdx.x * blockDim.x + threadIdx.x;   // float4 index
    if (i < 8 * 65536) {
        float4 v = ((const float4*)x)[i];
        int b = i >> 16, off = i & 65535;
        ((float4*)out)[(size_t)b * (NSLICE * 65536) + off] = v;
        f16x4 h = { (half_t)v.x, (half_t)v.y, (half_t)v.z, (half_t)v.w };
        *(f16x4*)&hbuf[(size_t)i * 4] = h;
    }
}

__global__ __launch_bounds__(256, 3)
void step_kernel(const float* __restrict__ state_base,
                 float* __restrict__ out_base,
                 const float* __restrict__ ws,
                 half_t* __restrict__ hbuf,
                 int t) {
    __shared__ half_t tile[86 * TSTR];   // 16512 B (2 pad rows absorb DMA overrun)

    const int tid = threadIdx.x;
    const int lane = tid & 63, w = tid >> 6;          // 4 waves
    const int X0 = blockIdx.x * 64, Y0 = blockIdx.y * 64, b = blockIdx.z;

    const float* __restrict__ in  = state_base + (size_t)(b * NSLICE + (t - 1)) * IMG;
    float* __restrict__ outp      = out_base   + (size_t)(b * NSLICE + t) * IMG;
    // fp16 state ping-pong: state t lives at parity t&1 (race-free across launches)
    const half_t* __restrict__ hin = hbuf + ((size_t)((t - 1) & 1) * 8 + b) * IMG;
    half_t* __restrict__ hout      = hbuf + ((size_t)(t & 1) * 8 + b) * IMG;

    // DMA-stage 84x96 fp16 tile: 16 chunks x 1024B; wave w -> chunks 4w..4w+3.
    // LDS dest wave-uniform (chunk base), global source per-lane (guide §5).
    #pragma unroll
    for (int i2 = 0; i2 < 4; ++i2) {
        int q = (w << 2) + i2;
        int h = (q << 9) + (lane << 3);     // half-index in linear tile
        int row = h / 96;
        int col = h - row * 96;
        int gr = (Y0 + row - 10) & MASK;
        int gc = (X0 + col - 16) & MASK;    // col mult of 8 -> 16B chunk, no wrap-cross
        __builtin_amdgcn_global_load_lds(
            (const __attribute__((address_space(1))) void*)(hin + gr * HW + gc),
            (__attribute__((address_space(3))) void*)&tile[q << 9],
            16, 0, 0);
    }

    // prefetch fp32 residual centers (L2-hot) while DMA flies
    const int gy0 = Y0 + 16 * w + (((lane >> 4) & 3) << 2);
    const int gxb = X0 + (lane & 15);
    float4 xv0, xv1, xv2, xv3;
    xv0.x = in[(gy0+0)*HW + gxb];      xv0.y = in[(gy0+1)*HW + gxb];
    xv0.z = in[(gy0+2)*HW + gxb];      xv0.w = in[(gy0+3)*HW + gxb];
    xv1.x = in[(gy0+0)*HW + gxb+16];   xv1.y = in[(gy0+1)*HW + gxb+16];
    xv1.z = in[(gy0+2)*HW + gxb+16];   xv1.w = in[(gy0+3)*HW + gxb+16];
    xv2.x = in[(gy0+0)*HW + gxb+32];   xv2.y = in[(gy0+1)*HW + gxb+32];
    xv2.z = in[(gy0+2)*HW + gxb+32];   xv2.w = in[(gy0+3)*HW + gxb+32];
    xv3.x = in[(gy0+0)*HW + gxb+48];   xv3.y = in[(gy0+1)*HW + gxb+48];
    xv3.z = in[(gy0+2)*HW + gxb+48];   xv3.w = in[(gy0+3)*HW + gxb+48];

    __syncthreads();    // compiler drains vmcnt(0) before barrier -> DMA complete

    const f16x8* bglob = (const f16x8*)((const unsigned short*)ws + WSB_OFF);
    const int rowoff = (16 * w + (lane & 15)) * TSTR + ((lane >> 4) << 3);

    f32x4 acc0 = {0.f,0.f,0.f,0.f}, acc1 = acc0, acc2 = acc0, acc3 = acc0;

    f16x8 a0,a1,a2,a3,a4;           // buffer A
    f16x8 c0,c1,c2,c3,c4;           // buffer C
    f16x8 b0h0,b0l0,b0h1,b0l1;      // B set 0
    f16x8 b1h0,b1l0,b1h1,b1l1;      // B set 1

    auto LOADA = [&](f16x8& h0, f16x8& h1, f16x8& h2, f16x8& h3, f16x8& h4,
                     int dy) {
        const half_t* rph = &tile[rowoff + dy * TSTR];
        h0 = *(const f16x8*)(rph);      h1 = *(const f16x8*)(rph + 16);
        h2 = *(const f16x8*)(rph + 32); h3 = *(const f16x8*)(rph + 48);
        h4 = *(const f16x8*)(rph + 64);
    };
    auto LOADB = [&](f16x8& h0, f16x8& l0, f16x8& h1, f16x8& l1, int dy) {
        const f16x8* nb = bglob + dy * 256 + lane;
        h0 = nb[0]; l0 = nb[64]; h1 = nb[128]; l1 = nb[192];
    };
    auto MFMA16 = [&](const f16x8& A0, const f16x8& A1, const f16x8& A2,
                      const f16x8& A3, const f16x8& A4,
                      const f16x8& bh0, const f16x8& bl0,
                      const f16x8& bh1, const f16x8& bl1) {
        __builtin_amdgcn_s_setprio(1);
        acc0 = __builtin_amdgcn_mfma_f32_16x16x32_f16(A0, bh0, acc0, 0,0,0);
        acc1 = __builtin_amdgcn_mfma_f32_16x16x32_f16(A1, bh0, acc1, 0,0,0);
        acc2 = __builtin_amdgcn_mfma_f32_16x16x32_f16(A2, bh0, acc2, 0,0,0);
        acc3 = __builtin_amdgcn_mfma_f32_16x16x32_f16(A3, bh0, acc3, 0,0,0);
        acc0 = __builtin_amdgcn_mfma_f32_16x16x32_f16(A1, bh1, acc0, 0,0,0);
        acc1 = __builtin_amdgcn_mfma_f32_16x16x32_f16(A2, bh1, acc1, 0,0,0);
        acc2 = __builtin_amdgcn_mfma_f32_16x16x32_f16(A3, bh1, acc2, 0,0,0);
        acc3 = __builtin_amdgcn_mfma_f32_16x16x32_f16(A4, bh1, acc3, 0,0,0);
        acc0 = __builtin_amdgcn_mfma_f32_16x16x32_f16(A0, bl0, acc0, 0,0,0);
        acc1 = __builtin_amdgcn_mfma_f32_16x16x32_f16(A1, bl0, acc1, 0,0,0);
        acc2 = __builtin_amdgcn_mfma_f32_16x16x32_f16(A2, bl0, acc2, 0,0,0);
        acc3 = __builtin_amdgcn_mfma_f32_16x16x32_f16(A3, bl0, acc3, 0,0,0);
        acc0 = __builtin_amdgcn_mfma_f32_16x16x32_f16(A1, bl1, acc0, 0,0,0);
        acc1 = __builtin_amdgcn_mfma_f32_16x16x32_f16(A2, bl1, acc1, 0,0,0);
        acc2 = __builtin_amdgcn_mfma_f32_16x16x32_f16(A3, bl1, acc2, 0,0,0);
        acc3 = __builtin_amdgcn_mfma_f32_16x16x32_f16(A4, bl1, acc3, 0,0,0);
        __builtin_amdgcn_s_setprio(0);
    };

    // prologue: dy=0 operands + dy=1 B-set
    LOADA(a0,a1,a2,a3,a4, 0);
    LOADB(b0h0,b0l0,b0h1,b0l1, 0);
    LOADB(b1h0,b1l0,b1h1,b1l1, 1);

    #pragma unroll 1
    for (int k = 0; k < 10; ++k) {
        const int dy1 = 2*k + 1;
        LOADA(c0,c1,c2,c3,c4, dy1);
        SBAR();
        MFMA16(a0,a1,a2,a3,a4, b0h0,b0l0,b0h1,b0l1);
        SBAR();
        LOADB(b0h0,b0l0,b0h1,b0l1, dy1 + 1);
        LOADA(a0,a1,a2,a3,a4, dy1 + 1);
        SBAR();
        MFMA16(c0,c1,c2,c3,c4, b1h0,b1l0,b1h1,b1l1);
        SBAR();
        if (k < 9) LOADB(b1h0,b1l0,b1h1,b1l1, dy1 + 2);
    }
    MFMA16(a0,a1,a2,a3,a4, b0h0,b0l0,b0h1,b0l1);         // dy = 20

    // D layout: lane l, reg q -> row = (l>>4)*4 + q, col = l&15 (dtype-indep)
    const float C = ws[0];
    auto EPI = [&](const f32x4& a4v, const float4& xv, int j) {
        int gx = gxb + 16 * j;
        float cv[4] = {xv.x, xv.y, xv.z, xv.w};
        #pragma unroll
        for (int q = 0; q < 4; ++q) {
            int gy = gy0 + q;
            float a  = cv[q] + C * fmaxf(a4v[q], 0.f);
            float e  = __expf(2.f * fabsf(a));        // tanh(|a|) = 1 - 2/(e+1)
            float r  = 1.f - 2.f * __builtin_amdgcn_rcpf(e + 1.f);
            float rv = copysignf(r, a);
            outp[gy * HW + gx] = rv;
            hout[gy * HW + gx] = (half_t)rv;          // fp16 state for next step
        }
    };
    EPI(acc0, xv0, 0); EPI(acc1, xv1, 1); EPI(acc2, xv2, 2); EPI(acc3, xv3, 3);
}

extern "C" void kernel_launch(void* const* d_in, const int* in_sizes, int n_in,
                              void* d_out, int out_size, void* d_ws, size_t ws_size,
                              hipStream_t stream) {
    const float* x  = (const float*)d_in[0];
    const float* w1 = (const float*)d_in[1];
    const float* w2 = (const float*)d_in[2];
    const float* w3 = (const float*)d_in[3];
    float* out = (float*)d_out;
    float* ws  = (float*)d_ws;
    half_t* hbuf = (half_t*)((char*)d_ws + HBUF_OFF_BYTES);

    prep_kernel<<<1, 256, 0, stream>>>(w1, w2, w3, ws);
    copy_kernel<<<2048, 256, 0, stream>>>(x, out, hbuf);

    dim3 grid(8, 8, 8);      // 512 blocks (64x64 out each); 16.5KB LDS -> 3/CU
    dim3 block(256);
    for (int t = 1; t <= NSTEP; ++t)
        step_kernel<<<grid, block, 0, stream>>>(out, out, ws, hbuf, t);
}

// Round 15
// 246.178 us; speedup vs baseline: 1.0792x; 1.0792x over previous
//
#include <hip/hip_runtime.h>
#include <hip/hip_fp16.h>
#include <math.h>

#define HW 512
#define MASK 511
#define IMG (512*512)
#define NSTEP 16
#define NSLICE 17

#define TR 84             // tile rows: [Y0-10, Y0+74)
#define TSTR 104          // ushort stride/row: 208 B = 13 granules (odd -> uniform banks)
#define WSB_OFF 32        // ushort offset of B-frag table in ws

typedef _Float16 half_t;
typedef __attribute__((ext_vector_type(8))) _Float16 f16x8;
typedef __attribute__((ext_vector_type(4))) float f32x4;

#define SBAR() __builtin_amdgcn_sched_barrier(0)

// B-frags (Toeplitz): frag f2 = dy*4 + v*2 + s  (v: dx-window, s: hi/lo split).
// lane l, elem j -> k = 8*(l>>4)+j, n = l&15, d = k-n.
// v=0: B[k][n] = W[dy][d-6]  for d in [6,15]  (dx 0..9,  A-window 16j)
// v=1: B[k][n] = W[dy][d+10] for d in [0,10]  (dx 10..20, A-window 16j+16)
// W = W_h + W_l (fp16 split) => W effectively exact; x is single fp16 (2-pass).
__global__ void prep_kernel(const float* __restrict__ w1,
                            const float* __restrict__ w2,
                            const float* __restrict__ w3,
                            float* __restrict__ ws) {
    int tid = threadIdx.x;
    if (tid == 0) {
        // 1->10->1 MLP on nonneg scalar collapses: C = sum_o w3[o]*max(w2[o],0)
        float c = 0.f;
        for (int o = 0; o < 10; ++o) c += w3[o] * fmaxf(w2[o], 0.f);
        ws[0] = c;
    }
    half_t* wsb = (half_t*)((unsigned short*)ws + WSB_OFF);
    for (int u = tid; u < 84 * 512; u += blockDim.x) {
        int f2 = u >> 9, rem = u & 511, l = rem >> 3, j = rem & 7;
        int dy = f2 >> 2, v = (f2 >> 1) & 1, s = f2 & 1;
        int k = ((l >> 4) << 3) + j, n = l & 15, d = k - n;
        float wf = 0.f;
        if (v == 0) { if (d >= 6 && d <= 15) wf = w1[dy * 21 + d - 6]; }
        else        { if (d >= 0 && d <= 10) wf = w1[dy * 21 + d + 10]; }
        half_t h = (half_t)wf;
        wsb[u] = (s == 0) ? h : (half_t)(wf - (float)h);   // W = W_h + W_l
    }
}

__global__ void copy_kernel(const float* __restrict__ x, float* __restrict__ out) {
    int i = blockIdx.x * blockDim.x + threadIdx.x;   // float4 index
    if (i < 8 * 65536) {
        const float4* in4 = (const float4*)x;
        float4* out4 = (float4*)out;
        int b = i >> 16;
        int off = i & 65535;
        out4[(size_t)b * (NSLICE * 65536) + off] = in4[i];
    }
}

__global__ __launch_bounds__(256, 3)
void step_kernel(const float* __restrict__ state_base,
                 float* __restrict__ out_base,
                 const float* __restrict__ ws,
                 int t) {
    __shared__ half_t tlh[TR * TSTR];   // x fp16 tile, 17472 B (single tile)

    const int tid = threadIdx.x;
    const int lane = tid & 63, w = tid >> 6;          // 4 waves
    const int X0 = blockIdx.x * 64, Y0 = blockIdx.y * 64, b = blockIdx.z;

    const float* __restrict__ in  = state_base + (size_t)(b * NSLICE + (t - 1)) * IMG;
    float* __restrict__ outp      = out_base   + (size_t)(b * NSLICE + t) * IMG;

    // stage 84 x 96 fp32 -> fp16 tile; cols gx in [X0-16, X0+80)
    for (int u = tid; u < TR * 12; u += 256) {
        int r = u / 12, ch = u - r * 12;
        int gr = (Y0 + r - 10) & MASK;
        int gc = X0 + 8 * ch - 16;
        float4 a  = *(const float4*)&in[gr * HW + (gc & MASK)];
        float4 c2 = *(const float4*)&in[gr * HW + ((gc + 4) & MASK)];
        float v[8] = {a.x, a.y, a.z, a.w, c2.x, c2.y, c2.z, c2.w};
        f16x8 hh;
        #pragma unroll
        for (int q = 0; q < 8; ++q) hh[q] = (half_t)v[q];
        *(f16x8*)&tlh[r * TSTR + 8 * ch] = hh;
    }

    // prefetch fp32 residual centers (L2-hot) while staging drains
    const int gy0 = Y0 + 16 * w + (((lane >> 4) & 3) << 2);
    const int gxb = X0 + (lane & 15);
    float4 xv0, xv1, xv2, xv3;
    xv0.x = in[(gy0+0)*HW + gxb];      xv0.y = in[(gy0+1)*HW + gxb];
    xv0.z = in[(gy0+2)*HW + gxb];      xv0.w = in[(gy0+3)*HW + gxb];
    xv1.x = in[(gy0+0)*HW + gxb+16];   xv1.y = in[(gy0+1)*HW + gxb+16];
    xv1.z = in[(gy0+2)*HW + gxb+16];   xv1.w = in[(gy0+3)*HW + gxb+16];
    xv2.x = in[(gy0+0)*HW + gxb+32];   xv2.y = in[(gy0+1)*HW + gxb+32];
    xv2.z = in[(gy0+2)*HW + gxb+32];   xv2.w = in[(gy0+3)*HW + gxb+32];
    xv3.x = in[(gy0+0)*HW + gxb+48];   xv3.y = in[(gy0+1)*HW + gxb+48];
    xv3.z = in[(gy0+2)*HW + gxb+48];   xv3.w = in[(gy0+3)*HW + gxb+48];

    __syncthreads();

    const f16x8* bglob = (const f16x8*)((const unsigned short*)ws + WSB_OFF);
    const int rowoff = (16 * w + (lane & 15)) * TSTR + ((lane >> 4) << 3);

    f32x4 acc0 = {0.f,0.f,0.f,0.f}, acc1 = acc0, acc2 = acc0, acc3 = acc0;

    // double-buffered A-frags (named regs) and B-sets
    f16x8 a0,a1,a2,a3,a4;           // buffer A
    f16x8 c0,c1,c2,c3,c4;           // buffer C
    f16x8 b0h0,b0l0,b0h1,b0l1;      // B set 0
    f16x8 b1h0,b1l0,b1h1,b1l1;      // B set 1

    auto LOADA = [&](f16x8& h0, f16x8& h1, f16x8& h2, f16x8& h3, f16x8& h4,
                     int dy) {
        const half_t* rph = &tlh[rowoff + dy * TSTR];
        h0 = *(const f16x8*)(rph);      h1 = *(const f16x8*)(rph + 16);
        h2 = *(const f16x8*)(rph + 32); h3 = *(const f16x8*)(rph + 48);
        h4 = *(const f16x8*)(rph + 64);
    };
    auto LOADB = [&](f16x8& h0, f16x8& l0, f16x8& h1, f16x8& l1, int dy) {
        const f16x8* nb = bglob + dy * 256 + lane;
        h0 = nb[0]; l0 = nb[64]; h1 = nb[128]; l1 = nb[192];
    };
    // NO s_setprio here (R15 A/B): prio-1 MFMA clusters starved the co-wave's
    // ds_read issue -> phase convoy -> LDS/matrix pipes serialized.
    auto MFMA16 = [&](const f16x8& A0, const f16x8& A1, const f16x8& A2,
                      const f16x8& A3, const f16x8& A4,
                      const f16x8& bh0, const f16x8& bl0,
                      const f16x8& bh1, const f16x8& bl1) {
        acc0 = __builtin_amdgcn_mfma_f32_16x16x32_f16(A0, bh0, acc0, 0,0,0);
        acc1 = __builtin_amdgcn_mfma_f32_16x16x32_f16(A1, bh0, acc1, 0,0,0);
        acc2 = __builtin_amdgcn_mfma_f32_16x16x32_f16(A2, bh0, acc2, 0,0,0);
        acc3 = __builtin_amdgcn_mfma_f32_16x16x32_f16(A3, bh0, acc3, 0,0,0);
        acc0 = __builtin_amdgcn_mfma_f32_16x16x32_f16(A1, bh1, acc0, 0,0,0);
        acc1 = __builtin_amdgcn_mfma_f32_16x16x32_f16(A2, bh1, acc1, 0,0,0);
        acc2 = __builtin_amdgcn_mfma_f32_16x16x32_f16(A3, bh1, acc2, 0,0,0);
        acc3 = __builtin_amdgcn_mfma_f32_16x16x32_f16(A4, bh1, acc3, 0,0,0);
        acc0 = __builtin_amdgcn_mfma_f32_16x16x32_f16(A0, bl0, acc0, 0,0,0);
        acc1 = __builtin_amdgcn_mfma_f32_16x16x32_f16(A1, bl0, acc1, 0,0,0);
        acc2 = __builtin_amdgcn_mfma_f32_16x16x32_f16(A2, bl0, acc2, 0,0,0);
        acc3 = __builtin_amdgcn_mfma_f32_16x16x32_f16(A3, bl0, acc3, 0,0,0);
        acc0 = __builtin_amdgcn_mfma_f32_16x16x32_f16(A1, bl1, acc0, 0,0,0);
        acc1 = __builtin_amdgcn_mfma_f32_16x16x32_f16(A2, bl1, acc1, 0,0,0);
        acc2 = __builtin_amdgcn_mfma_f32_16x16x32_f16(A3, bl1, acc2, 0,0,0);
        acc3 = __builtin_amdgcn_mfma_f32_16x16x32_f16(A4, bl1, acc3, 0,0,0);
    };

    // prologue: dy=0 operands + dy=1 B-set
    LOADA(a0,a1,a2,a3,a4, 0);
    LOADB(b0h0,b0l0,b0h1,b0l1, 0);
    LOADB(b1h0,b1l0,b1h1,b1l1, 1);

    #pragma unroll 1
    for (int k = 0; k < 10; ++k) {
        const int dy1 = 2*k + 1;
        // --- half 1: issue dy1 A-reads, then MFMA dy=2k ---
        LOADA(c0,c1,c2,c3,c4, dy1);
        SBAR();
        MFMA16(a0,a1,a2,a3,a4, b0h0,b0l0,b0h1,b0l1);
        SBAR();
        // --- half 2: issue dy1+1 A-reads + B-loads, then MFMA dy=2k+1 ---
        LOADB(b0h0,b0l0,b0h1,b0l1, dy1 + 1);
        LOADA(a0,a1,a2,a3,a4, dy1 + 1);
        SBAR();
        MFMA16(c0,c1,c2,c3,c4, b1h0,b1l0,b1h1,b1l1);
        SBAR();
        if (k < 9) LOADB(b1h0,b1l0,b1h1,b1l1, dy1 + 2);
    }
    MFMA16(a0,a1,a2,a3,a4, b0h0,b0l0,b0h1,b0l1);         // dy = 20

    // D layout: lane l, reg q -> row = (l>>4)*4 + q, col = l&15 (dtype-indep)
    const float C = ws[0];
    auto EPI = [&](const f32x4& a4v, const float4& xv, int j) {
        int gx = gxb + 16 * j;
        float cv[4] = {xv.x, xv.y, xv.z, xv.w};
        #pragma unroll
        for (int q = 0; q < 4; ++q) {
            int gy = gy0 + q;
            float a  = cv[q] + C * fmaxf(a4v[q], 0.f);
            float e  = __expf(2.f * fabsf(a));        // tanh(|a|) = 1 - 2/(e+1)
            float r  = 1.f - 2.f * __builtin_amdgcn_rcpf(e + 1.f);
            outp[gy * HW + gx] = copysignf(r, a);
        }
    };
    EPI(acc0, xv0, 0); EPI(acc1, xv1, 1); EPI(acc2, xv2, 2); EPI(acc3, xv3, 3);
}

extern "C" void kernel_launch(void* const* d_in, const int* in_sizes, int n_in,
                              void* d_out, int out_size, void* d_ws, size_t ws_size,
                              hipStream_t stream) {
    const float* x  = (const float*)d_in[0];
    const float* w1 = (const float*)d_in[1];
    const float* w2 = (const float*)d_in[2];
    const float* w3 = (const float*)d_in[3];
    float* out = (float*)d_out;
    float* ws  = (float*)d_ws;

    prep_kernel<<<1, 256, 0, stream>>>(w1, w2, w3, ws);
    copy_kernel<<<2048, 256, 0, stream>>>(x, out);

    dim3 grid(8, 8, 8);      // 512 blocks (64x64 out each) = 2/CU
    dim3 block(256);
    for (int t = 1; t <= NSTEP; ++t)
        step_kernel<<<grid, block, 0, stream>>>(out, out, ws, t);
}